// Round 23
// baseline (806.880 us; speedup 1.0000x reference)
//
#include <hip/hip_runtime.h>
#include <math.h>

#define DIM 512
#define NCLS 100
#define NS 2048
#define DD (DIM*DIM)
#define SHRINKV 1e-4f

typedef short bf16x8 __attribute__((ext_vector_type(8)));
typedef short s16x4 __attribute__((ext_vector_type(4)));
typedef float f32x4 __attribute__((ext_vector_type(4)));

static __device__ __forceinline__ short f2bf(float f) {
  unsigned int u = __float_as_uint(f);
  u += 0x7FFFu + ((u >> 16) & 1u);   // round-to-nearest-even
  return (short)(u >> 16);
}

// bijective XCD-contiguous remap (m204)
static __device__ __forceinline__ int xcd_swz(int bid, int nwg) {
  int xcd = bid & 7, idx = bid >> 3;
  int q = nwg >> 3, r = nwg & 7;
  return (xcd < r ? xcd * (q + 1) : r * (q + 1) + (xcd - r) * q) + idx;
}

// Build M_k = (1-sh)*(0.5*(SigmaK_k+Sigma)) + sh*I ; accumulate ||RegSigma||_F^2
__global__ __launch_bounds__(256) void prep_kernel(const float* __restrict__ SigmaK,
                                                   const float* __restrict__ Sigma,
                                                   float* __restrict__ M,
                                                   float* __restrict__ aux) {
  int b = blockIdx.x;
  int k = b >> 2, chunk = b & 3;
  const float* Sk = SigmaK + (size_t)k * DD;
  float* Mk = M + (size_t)k * DD;
  int base0 = chunk << 16;
  float fro = 0.f;
  const float oms = 1.0f - SHRINKV;
  for (int it = 0; it < 64; ++it) {
    int idx = base0 + (it << 10) + (threadIdx.x << 2);
    float4 a = *(const float4*)(Sk + idx);
    float4 g = *(const float4*)(Sigma + idx);
    int r = idx >> 9, c = idx & 511;
    float4 reg;
    reg.x = 0.5f*(a.x + g.x); reg.y = 0.5f*(a.y + g.y);
    reg.z = 0.5f*(a.z + g.z); reg.w = 0.5f*(a.w + g.w);
    fro += reg.x*reg.x + reg.y*reg.y + reg.z*reg.z + reg.w*reg.w;
    float4 m;
    m.x = oms*reg.x + ((r == c + 0) ? SHRINKV : 0.f);
    m.y = oms*reg.y + ((r == c + 1) ? SHRINKV : 0.f);
    m.z = oms*reg.z + ((r == c + 2) ? SHRINKV : 0.f);
    m.w = oms*reg.w + ((r == c + 3) ? SHRINKV : 0.f);
    *(float4*)(Mk + idx) = m;
  }
  __shared__ float red[4];
  int lane = threadIdx.x & 63, w = threadIdx.x >> 6;
  for (int o = 32; o > 0; o >>= 1) fro += __shfl_down(fro, o);
  if (lane == 0) red[w] = fro;
  __syncthreads();
  if (threadIdx.x == 0) atomicAdd(&aux[1 + k], red[0] + red[1] + red[2] + red[3]);
}

// Single-wave diag factor + triangular inverse for panel at p0 (no barriers).
static __device__ __forceinline__ void fdiag_dev(float* __restrict__ Mk,
                                                 short* __restrict__ Wk,
                                                 int p0, int lane,
                                                 float* __restrict__ Llds) {
  float row[64];
  const float* src = Mk + (size_t)(p0 + lane) * DIM + p0;
  #pragma unroll
  for (int c4 = 0; c4 < 64; c4 += 4) {
    float4 v = *(const float4*)(src + c4);
    row[c4] = v.x; row[c4+1] = v.y; row[c4+2] = v.z; row[c4+3] = v.w;
  }
  #pragma unroll
  for (int j = 0; j < 64; ++j) {
    float diagv = __shfl(row[j], j);
    float dv = sqrtf(diagv);
    float rinv = 1.0f / dv;
    float myLj = row[j] * rinv;
    row[j] = myLj;
    #pragma unroll
    for (int c = j + 1; c < 64; ++c)
      row[c] = fmaf(-myLj, __shfl(myLj, c), row[c]);
  }
  #pragma unroll
  for (int c = 0; c < 64; ++c)
    Llds[lane * 68 + c] = (c <= lane) ? row[c] : 0.f;
  float w[64];
  #pragma unroll
  for (int r = 0; r < 64; ++r) {
    float s = 0.f;
    #pragma unroll
    for (int kk = 0; kk + 4 <= r; kk += 4) {
      float4 lv = *(const float4*)(Llds + r*68 + kk);
      s += lv.x*w[kk] + lv.y*w[kk+1] + lv.z*w[kk+2] + lv.w*w[kk+3];
    }
    #pragma unroll
    for (int kk = r & ~3; kk < r; ++kk) s += Llds[r*68 + kk] * w[kk];
    float rhs = ((r == lane) ? 1.0f : 0.0f) - s;
    w[r] = rhs / Llds[r*68 + r];   // exact 0 for r < lane
  }
  #pragma unroll
  for (int r = 0; r < 64; ++r) {
    Mk[(size_t)(p0 + r)*DIM + p0 + lane] = w[r];
    Wk[(size_t)(p0 + r)*DIM + p0 + lane] = f2bf(w[r]);
  }
}

// Standalone fdiag for panel 0. One wave per class.
__global__ __launch_bounds__(64) void fdiag_kernel(float* __restrict__ M,
                                                   short* __restrict__ Wb) {
  __shared__ float Llds[64 * 68];
  fdiag_dev(M + (size_t)blockIdx.x * DD, Wb + (size_t)blockIdx.x * DD,
            0, threadIdx.x, Llds);
}

// Panel launch p (grid = NCLS*7):
//  WG r<n (n=7-p): TRSM i=p+1+r; r==0 folds (p+1,p+1) self-update; at p==6
//    also chains fdiag(7).
//  WG r>=n: sweeprow j=r-n (<p): W_pj = -W_pp * sum_{k=j}^{p-1} L_pk W_kj.
//  p==7 launch (n=0): ALL 7 WGs run sweeprow for row 7 (j=0..6) — inputs
//    (L_7k from trsm(6), inv(7) chained there) complete before this launch.
__global__ __launch_bounds__(256) void trsm_kernel(float* __restrict__ M,
                                                   short* __restrict__ Wb, int p) {
  __shared__ float SA[2][64 * 68];
  __shared__ float SB[2][64 * 68];
  int n = 7 - p;
  int wg = xcd_swz(blockIdx.x, NCLS * 7);
  int cls = wg / 7, r = wg % 7;
  float* Mk = M + (size_t)cls * DD;
  short* Wk = Wb + (size_t)cls * DD;
  int tid = threadIdx.x;
  int ty = tid >> 4, tx = tid & 15;
  int sr = tid >> 2, sq = (tid & 3) << 4;
  int p0 = p << 6;

  if (r < n) {
    // ---- TRSM path ----
    int i = p + 1 + r;
    {
      const float* a = Mk + (size_t)((i << 6) + sr)*DIM + p0 + sq;
      const float* b = Mk + (size_t)(p0 + sr)*DIM + p0 + sq;   // inv(p)
      #pragma unroll
      for (int t4 = 0; t4 < 4; ++t4) {
        float4 va = *(const float4*)(a + 4*t4);
        SA[0][(sq+4*t4+0)*68+sr]=va.x; SA[0][(sq+4*t4+1)*68+sr]=va.y;
        SA[0][(sq+4*t4+2)*68+sr]=va.z; SA[0][(sq+4*t4+3)*68+sr]=va.w;
        float4 vb = *(const float4*)(b + 4*t4);
        SA[1][(sq+4*t4+0)*68+sr]=vb.x; SA[1][(sq+4*t4+1)*68+sr]=vb.y;
        SA[1][(sq+4*t4+2)*68+sr]=vb.z; SA[1][(sq+4*t4+3)*68+sr]=vb.w;
      }
    }
    __syncthreads();
    float acc[4][4];
    #pragma unroll
    for (int a2 = 0; a2 < 4; ++a2)
      #pragma unroll
      for (int b2 = 0; b2 < 4; ++b2) acc[a2][b2] = 0.f;
    #pragma unroll 16
    for (int m = 0; m < 64; ++m) {
      float4 av = *(const float4*)(&SA[0][m*68 + (ty << 2)]);
      float4 bv = *(const float4*)(&SA[1][m*68 + (tx << 2)]);
      float a4[4] = {av.x, av.y, av.z, av.w};
      float b4[4] = {bv.x, bv.y, bv.z, bv.w};
      #pragma unroll
      for (int ir = 0; ir < 4; ++ir)
        #pragma unroll
        for (int ic = 0; ic < 4; ++ic) acc[ir][ic] += a4[ir] * b4[ic];
    }
    #pragma unroll
    for (int q = 0; q < 4; ++q) {
      float4 v; v.x = acc[q][0]; v.y = acc[q][1]; v.z = acc[q][2]; v.w = acc[q][3];
      *(float4*)(Mk + (size_t)((i << 6) + (ty << 2) + q)*DIM + p0 + (tx << 2)) = v;
    }
    if (r == 0) {   // fold syrk of (p+1,p+1): C -= L*L^T
      __syncthreads();
      #pragma unroll
      for (int q = 0; q < 4; ++q)
        #pragma unroll
        for (int cc = 0; cc < 4; ++cc)
          SA[0][((tx << 2) + cc)*68 + (ty << 2) + q] = acc[q][cc];   // [m][r]=L[r][m]
      __syncthreads();
      float s2[4][4];
      #pragma unroll
      for (int a2 = 0; a2 < 4; ++a2)
        #pragma unroll
        for (int b2 = 0; b2 < 4; ++b2) s2[a2][b2] = 0.f;
      #pragma unroll 16
      for (int m = 0; m < 64; ++m) {
        float4 av = *(const float4*)(&SA[0][m*68 + (ty << 2)]);
        float4 bv = *(const float4*)(&SA[0][m*68 + (tx << 2)]);
        float a4[4] = {av.x, av.y, av.z, av.w};
        float b4[4] = {bv.x, bv.y, bv.z, bv.w};
        #pragma unroll
        for (int ir = 0; ir < 4; ++ir)
          #pragma unroll
          for (int ic = 0; ic < 4; ++ic) s2[ir][ic] += a4[ir] * b4[ic];
      }
      int d0 = (p + 1) << 6;
      #pragma unroll
      for (int q = 0; q < 4; ++q) {
        float* dst = Mk + (size_t)(d0 + (ty << 2) + q)*DIM + d0 + (tx << 2);
        float4 v = *(const float4*)dst;
        v.x -= s2[q][0]; v.y -= s2[q][1]; v.z -= s2[q][2]; v.w -= s2[q][3];
        *(float4*)dst = v;
      }
      if (p == 6) {                 // last panel: chain fdiag(7)
        __syncthreads();
        if (tid < 64)
          fdiag_dev(Mk, Wk, d0, tid, SA[1]);
      }
    }
  } else {
    // ---- sweeprow path: j = r - n  (j < p) ----
    int j = r - n;
    auto stageLW = [&](int k, int buf) {
      const float* a = Mk + (size_t)(p0 + sr)*DIM + (k << 6) + sq;          // L_pk
      const float* b = Mk + (size_t)((j << 6) + sr)*DIM + (k << 6) + sq;    // W_kj
      #pragma unroll
      for (int t4 = 0; t4 < 4; ++t4) {
        float4 va = *(const float4*)(a + 4*t4);
        SA[buf][(sq+4*t4+0)*68+sr]=va.x; SA[buf][(sq+4*t4+1)*68+sr]=va.y;
        SA[buf][(sq+4*t4+2)*68+sr]=va.z; SA[buf][(sq+4*t4+3)*68+sr]=va.w;
        *(float4*)(&SB[buf][sr*68 + sq + 4*t4]) = *(const float4*)(b + 4*t4);
      }
    };
    float acc[4][4];
    #pragma unroll
    for (int a = 0; a < 4; ++a)
      #pragma unroll
      for (int b = 0; b < 4; ++b) acc[a][b] = 0.f;
    stageLW(j, 0);
    __syncthreads();
    int cur = 0;
    for (int k = j; k < p; ++k) {
      if (k + 1 < p) stageLW(k + 1, cur ^ 1);
      #pragma unroll 16
      for (int m = 0; m < 64; ++m) {
        float4 av = *(const float4*)(&SA[cur][m*68 + (ty << 2)]);
        float4 bv = *(const float4*)(&SB[cur][m*68 + (tx << 2)]);
        float a4[4] = {av.x, av.y, av.z, av.w};
        float b4[4] = {bv.x, bv.y, bv.z, bv.w};
        #pragma unroll
        for (int ir = 0; ir < 4; ++ir)
          #pragma unroll
          for (int ic = 0; ic < 4; ++ic) acc[ir][ic] += a4[ir] * b4[ic];
      }
      __syncthreads();
      cur ^= 1;
    }
    #pragma unroll
    for (int q = 0; q < 4; ++q) {
      float4 v; v.x = acc[q][0]; v.y = acc[q][1]; v.z = acc[q][2]; v.w = acc[q][3];
      *(float4*)(&SB[0][((ty << 2) + q)*68 + (tx << 2)]) = v;
    }
    {
      const float* a = Mk + (size_t)(p0 + sr)*DIM + p0 + sq;   // W_pp = inv(p)
      #pragma unroll
      for (int t4 = 0; t4 < 4; ++t4) {
        float4 va = *(const float4*)(a + 4*t4);
        SA[0][(sq+4*t4+0)*68+sr]=va.x; SA[0][(sq+4*t4+1)*68+sr]=va.y;
        SA[0][(sq+4*t4+2)*68+sr]=va.z; SA[0][(sq+4*t4+3)*68+sr]=va.w;
      }
    }
    __syncthreads();
    float r2[4][4];
    #pragma unroll
    for (int a = 0; a < 4; ++a)
      #pragma unroll
      for (int b = 0; b < 4; ++b) r2[a][b] = 0.f;
    #pragma unroll 16
    for (int m = 0; m < 64; ++m) {
      float4 av = *(const float4*)(&SA[0][m*68 + (ty << 2)]);
      float4 bv = *(const float4*)(&SB[0][m*68 + (tx << 2)]);
      float a4[4] = {av.x, av.y, av.z, av.w};
      float b4[4] = {bv.x, bv.y, bv.z, bv.w};
      #pragma unroll
      for (int ir = 0; ir < 4; ++ir)
        #pragma unroll
        for (int ic = 0; ic < 4; ++ic) r2[ir][ic] += a4[ir] * b4[ic];
    }
    #pragma unroll
    for (int q = 0; q < 4; ++q) {
      int a = (ty << 2) + q;
      float4 v; v.x = -r2[q][0]; v.y = -r2[q][1]; v.z = -r2[q][2]; v.w = -r2[q][3];
      *(float4*)(Mk + (size_t)((j << 6) + a)*DIM + p0 + (tx << 2)) = v;     // upper (j,p)
      s16x4 h;
      h[0] = f2bf(v.x); h[1] = f2bf(v.y); h[2] = f2bf(v.z); h[3] = f2bf(v.w);
      *(s16x4*)(Wk + (size_t)(p0 + a)*DIM + (j << 6) + (tx << 2)) = h;      // bf16 (p,j)
    }
  }
}

// Combined launch for panel p: syrkR(p) (all pairs except (p+1,p+1)) in the
// first NCLS*(T-1) WGs, fdiag(p+1) in the last NCLS WGs (hidden under syrk).
__global__ __launch_bounds__(256) void combo_kernel(float* __restrict__ M,
                                                    short* __restrict__ Wb, int p) {
  __shared__ float TA[64 * 68];
  __shared__ float TB[64 * 68];
  int n = 7 - p;
  int T = n * (n + 1) / 2;
  int nsyrk = NCLS * (T - 1);
  int wg = xcd_swz(blockIdx.x, nsyrk + NCLS);
  int tid = threadIdx.x;
  if (wg >= nsyrk) {   // fdiag(p+1)
    int cls = wg - nsyrk;
    if (tid < 64)
      fdiag_dev(M + (size_t)cls * DD, Wb + (size_t)cls * DD,
                (p + 1) << 6, tid, TA);
    return;
  }
  int cls = wg / (T - 1);
  int t = wg % (T - 1) + 1;   // skip t=0 = (p+1,p+1), folded into trsm
  int bi = 0;
  while (t > bi) { t -= bi + 1; ++bi; }
  int i = p + 1 + bi, j = p + 1 + t;
  float* Mk = M + (size_t)cls * DD;
  int ty = tid >> 4, tx = tid & 15;
  int sr = tid >> 2, sq = (tid & 3) << 4;
  {
    const float* a = Mk + (size_t)((i << 6) + sr)*DIM + (p << 6) + sq;
    const float* b = Mk + (size_t)((j << 6) + sr)*DIM + (p << 6) + sq;
    #pragma unroll
    for (int t4 = 0; t4 < 4; ++t4) {
      float4 va = *(const float4*)(a + 4*t4);
      TA[(sq+4*t4+0)*68+sr]=va.x; TA[(sq+4*t4+1)*68+sr]=va.y;
      TA[(sq+4*t4+2)*68+sr]=va.z; TA[(sq+4*t4+3)*68+sr]=va.w;
      float4 vb = *(const float4*)(b + 4*t4);
      TB[(sq+4*t4+0)*68+sr]=vb.x; TB[(sq+4*t4+1)*68+sr]=vb.y;
      TB[(sq+4*t4+2)*68+sr]=vb.z; TB[(sq+4*t4+3)*68+sr]=vb.w;
    }
  }
  __syncthreads();
  float acc[4][4];
  #pragma unroll
  for (int a = 0; a < 4; ++a)
    #pragma unroll
    for (int b = 0; b < 4; ++b) acc[a][b] = 0.f;
  #pragma unroll 16
  for (int m = 0; m < 64; ++m) {
    float4 av = *(const float4*)(TA + m*68 + (ty << 2));
    float4 bv = *(const float4*)(TB + m*68 + (tx << 2));
    float a4[4] = {av.x, av.y, av.z, av.w};
    float b4[4] = {bv.x, bv.y, bv.z, bv.w};
    #pragma unroll
    for (int ir = 0; ir < 4; ++ir)
      #pragma unroll
      for (int ic = 0; ic < 4; ++ic) acc[ir][ic] += a4[ir] * b4[ic];
  }
  #pragma unroll
  for (int q = 0; q < 4; ++q) {
    float* dst = Mk + (size_t)((i << 6) + (ty << 2) + q)*DIM + (j << 6) + (tx << 2);
    float4 v = *(const float4*)dst;
    v.x -= acc[q][0]; v.y -= acc[q][1]; v.z -= acc[q][2]; v.w -= acc[q][3];
    *(float4*)dst = v;
  }
}

// scores via bf16 MFMA. 8-slot ring, TWO tiles per barrier (18 barriers),
// issue -> vmcnt -> barrier ordering (round-21 verified: each wave's tiles
// land before the barrier, so the barrier publishes all 4 waves' chunks).
__global__ __launch_bounds__(256) void score_kernel(const float* __restrict__ X,
                                                    const float* __restrict__ muK,
                                                    const float* __restrict__ cK,
                                                    const short* __restrict__ W,
                                                    const float* __restrict__ aux,
                                                    float* __restrict__ out) {
  __shared__ __align__(16) char WB8[8][8192];   // 64 KB ring
  __shared__ float sred[4];
  int bid = blockIdx.x;
  int wg = ((bid & 7) * 400) + (bid >> 3);   // XCD swizzle (3200 = 8*400)
  int kc = wg >> 5;
  int n0 = (wg & 31) << 6;
  int tid = threadIdx.x;
  int lane = tid & 63, wv = tid >> 6;
  const short* Wk = W + (size_t)kc * DD;
  const float* mu = muK + (size_t)kc * DIM;
  int r16 = lane & 15;
  int k8 = (lane >> 4) << 3;
  int arow = (wv << 4) + r16;

  int lrow = lane >> 3;
  int lcolel = ((lane & 7) ^ lrow) << 3;

  constexpr int SJT[36] = {0,1,1, 2,3,2,3,2,3,3, 4,5,4,5,4,5,4,5,4,5,5,
                           6,7,6,7,6,7,6,7,6,7,6,7,6,7,7};
  constexpr int SDC[36] = {0,0,1, 0,0,1,1,2,2,3, 0,0,1,1,2,2,3,3,4,4,5,
                           0,0,1,1,2,2,3,3,4,4,5,5,6,6,7};

  bf16x8 af[8][2];
  #pragma unroll
  for (int dc = 0; dc < 8; ++dc) {
    #pragma unroll
    for (int ks = 0; ks < 2; ++ks) {
      int col = (dc << 6) + (ks << 5) + k8;
      const float* xp = X + (size_t)(n0 + arow)*DIM + col;
      float4 x0 = *(const float4*)xp;
      float4 x1 = *(const float4*)(xp + 4);
      float4 m0 = *(const float4*)(mu + col);
      float4 m1 = *(const float4*)(mu + col + 4);
      bf16x8 h;
      h[0]=f2bf(x0.x-m0.x); h[1]=f2bf(x0.y-m0.y); h[2]=f2bf(x0.z-m0.z); h[3]=f2bf(x0.w-m0.w);
      h[4]=f2bf(x1.x-m1.x); h[5]=f2bf(x1.y-m1.y); h[6]=f2bf(x1.z-m1.z); h[7]=f2bf(x1.w-m1.w);
      af[dc][ks] = h;
    }
  }

  auto issue = [&](int s) {
    const int b = s & 7;
    const int rbase = SJT[s] << 6;
    const int cc = (SDC[s] << 6) + lcolel;
    #pragma unroll
    for (int q = 0; q < 2; ++q) {
      const short* g = Wk + (size_t)(rbase + (q << 5) + (wv << 3) + lrow)*DIM + cc;
      __builtin_amdgcn_global_load_lds(
          (const __attribute__((address_space(1))) void*)g,
          (__attribute__((address_space(3))) void*)(WB8[b] + (q << 12) + (wv << 10)),
          16, 0, 0);
    }
  };

  float qp[4] = {0.f, 0.f, 0.f, 0.f};
  f32x4 acc[2][4];
  #pragma unroll
  for (int a = 0; a < 2; ++a)
    #pragma unroll
    for (int jj = 0; jj < 4; ++jj) { acc[a][jj][0]=0.f; acc[a][jj][1]=0.f; acc[a][jj][2]=0.f; acc[a][jj][3]=0.f; }

  issue(0);
  issue(1);
  issue(2);
  issue(3);
  #pragma unroll
  for (int s = 0; s < 36; ++s) {
    const int jt = SJT[s], dc = SDC[s];
    if ((s & 1) == 0) {                       // one barrier per tile PAIR
      if (s + 4 < 36) issue(s + 4);
      if (s + 5 < 36) issue(s + 5);
      if (s <= 30)      asm volatile("s_waitcnt vmcnt(8)" ::: "memory");
      else if (s == 32) asm volatile("s_waitcnt vmcnt(4)" ::: "memory");
      else              asm volatile("s_waitcnt vmcnt(0)" ::: "memory");
      __builtin_amdgcn_s_barrier();           // tiles s, s+1 visible
      __builtin_amdgcn_sched_barrier(0);      // rule 18
    }
    __builtin_amdgcn_s_setprio(1);
    #pragma unroll
    for (int ks = 0; ks < 2; ++ks) {
      #pragma unroll
      for (int jj = 0; jj < 4; ++jj) {
        int brow = (jj << 4) + r16;
        bf16x8 bfr = *(const bf16x8*)((const char*)WB8[s & 7] +
                     (((brow << 7) + (((ks << 5) + k8) << 1)) ^ ((brow & 7) << 4)));
        acc[jt & 1][jj] = __builtin_amdgcn_mfma_f32_16x16x32_bf16(af[dc][ks], bfr, acc[jt & 1][jj], 0, 0, 0);
      }
    }
    __builtin_amdgcn_s_setprio(0);
    if (s == 2 || s == 9 || s == 20 || s == 35) {   // group end: square & reset
      #pragma unroll
      for (int a = 0; a < 2; ++a)
        #pragma unroll
        for (int jj = 0; jj < 4; ++jj)
          #pragma unroll
          for (int r = 0; r < 4; ++r) {
            float y = acc[a][jj][r]; qp[r] += y * y;
            acc[a][jj][r] = 0.f;
          }
    }
  }
  #pragma unroll
  for (int r = 0; r < 4; ++r) {
    qp[r] += __shfl_xor(qp[r], 1);
    qp[r] += __shfl_xor(qp[r], 2);
    qp[r] += __shfl_xor(qp[r], 4);
    qp[r] += __shfl_xor(qp[r], 8);
  }
  {
    float v = (tid < NCLS) ? cK[tid] : 0.f;
    #pragma unroll
    for (int o = 32; o > 0; o >>= 1) v += __shfl_xor(v, o);
    if (lane == 0) sred[wv] = v;
  }
  __syncthreads();
  float sumck = sred[0] + sred[1] + sred[2] + sred[3];
  float ck = cK[kc];
  float base;
  if (ck == 0.f) base = -INFINITY;
  else base = logf(ck) - logf(sumck) - 0.25f * logf(aux[1 + kc]);
  if ((lane & 15) == 0) {
    int nbase = n0 + (wv << 4) + ((lane >> 4) << 2);
    #pragma unroll
    for (int r = 0; r < 4; ++r)
      out[(size_t)(nbase + r)*NCLS + kc] = base - 0.5f * qp[r];
  }
}

extern "C" void kernel_launch(void* const* d_in, const int* in_sizes, int n_in,
                              void* d_out, int out_size, void* d_ws, size_t ws_size,
                              hipStream_t stream) {
  (void)in_sizes; (void)n_in; (void)out_size; (void)ws_size;
  const float* X      = (const float*)d_in[0];
  const float* muK    = (const float*)d_in[1];
  const float* SigmaK = (const float*)d_in[2];
  const float* Sigma  = (const float*)d_in[3];
  const float* cK     = (const float*)d_in[4];
  float* out = (float*)d_out;
  char* ws = (char*)d_ws;
  float* M   = (float*)ws;                                   // 104857600 B
  short* W   = (short*)(ws + (size_t)NCLS * DD * 4);         //  52428800 B
  float* aux = (float*)(ws + (size_t)NCLS * DD * 6);         //       404 B

  (void)hipMemsetAsync(aux, 0, (1 + NCLS) * sizeof(float), stream);
  prep_kernel<<<400, 256, 0, stream>>>(SigmaK, Sigma, M, aux);
  fdiag_kernel<<<NCLS, 64, 0, stream>>>(M, W);               // inv(0)
  for (int p = 0; p < 7; ++p) {
    int n = 7 - p;
    int T = n * (n + 1) / 2;
    trsm_kernel<<<NCLS * 7, 256, 0, stream>>>(M, W, p);      // trsm + sweeprow
    if (p < 6)
      combo_kernel<<<NCLS * (T - 1) + NCLS, 256, 0, stream>>>(M, W, p);  // syrkR ∥ fdiag(p+1)
  }
  trsm_kernel<<<NCLS * 7, 256, 0, stream>>>(M, W, 7);        // sweeprow row 7
  score_kernel<<<NCLS * 32, 256, 0, stream>>>(X, muK, cK, W, aux, out);
}

// Round 24
// 738.491 us; speedup vs baseline: 1.0926x; 1.0926x over previous
//
#include <hip/hip_runtime.h>
#include <math.h>

#define DIM 512
#define NCLS 100
#define NS 2048
#define DD (DIM*DIM)
#define SHRINKV 1e-4f

typedef short bf16x8 __attribute__((ext_vector_type(8)));
typedef short s16x4 __attribute__((ext_vector_type(4)));
typedef float f32x4 __attribute__((ext_vector_type(4)));

static __device__ __forceinline__ short f2bf(float f) {
  unsigned int u = __float_as_uint(f);
  u += 0x7FFFu + ((u >> 16) & 1u);   // round-to-nearest-even
  return (short)(u >> 16);
}

// bijective XCD-contiguous remap (m204)
static __device__ __forceinline__ int xcd_swz(int bid, int nwg) {
  int xcd = bid & 7, idx = bid >> 3;
  int q = nwg >> 3, r = nwg & 7;
  return (xcd < r ? xcd * (q + 1) : r * (q + 1) + (xcd - r) * q) + idx;
}

// Build M_k = (1-sh)*(0.5*(SigmaK_k+Sigma)) + sh*I ; accumulate ||RegSigma||_F^2
__global__ __launch_bounds__(256) void prep_kernel(const float* __restrict__ SigmaK,
                                                   const float* __restrict__ Sigma,
                                                   float* __restrict__ M,
                                                   float* __restrict__ aux) {
  int b = blockIdx.x;
  int k = b >> 2, chunk = b & 3;
  const float* Sk = SigmaK + (size_t)k * DD;
  float* Mk = M + (size_t)k * DD;
  int base0 = chunk << 16;
  float fro = 0.f;
  const float oms = 1.0f - SHRINKV;
  for (int it = 0; it < 64; ++it) {
    int idx = base0 + (it << 10) + (threadIdx.x << 2);
    float4 a = *(const float4*)(Sk + idx);
    float4 g = *(const float4*)(Sigma + idx);
    int r = idx >> 9, c = idx & 511;
    float4 reg;
    reg.x = 0.5f*(a.x + g.x); reg.y = 0.5f*(a.y + g.y);
    reg.z = 0.5f*(a.z + g.z); reg.w = 0.5f*(a.w + g.w);
    fro += reg.x*reg.x + reg.y*reg.y + reg.z*reg.z + reg.w*reg.w;
    float4 m;
    m.x = oms*reg.x + ((r == c + 0) ? SHRINKV : 0.f);
    m.y = oms*reg.y + ((r == c + 1) ? SHRINKV : 0.f);
    m.z = oms*reg.z + ((r == c + 2) ? SHRINKV : 0.f);
    m.w = oms*reg.w + ((r == c + 3) ? SHRINKV : 0.f);
    *(float4*)(Mk + idx) = m;
  }
  __shared__ float red[4];
  int lane = threadIdx.x & 63, w = threadIdx.x >> 6;
  for (int o = 32; o > 0; o >>= 1) fro += __shfl_down(fro, o);
  if (lane == 0) red[w] = fro;
  __syncthreads();
  if (threadIdx.x == 0) atomicAdd(&aux[1 + k], red[0] + red[1] + red[2] + red[3]);
}

// Single-wave diag factor + triangular inverse for panel at p0 (no barriers).
static __device__ __forceinline__ void fdiag_dev(float* __restrict__ Mk,
                                                 short* __restrict__ Wk,
                                                 int p0, int lane,
                                                 float* __restrict__ Llds) {
  float row[64];
  const float* src = Mk + (size_t)(p0 + lane) * DIM + p0;
  #pragma unroll
  for (int c4 = 0; c4 < 64; c4 += 4) {
    float4 v = *(const float4*)(src + c4);
    row[c4] = v.x; row[c4+1] = v.y; row[c4+2] = v.z; row[c4+3] = v.w;
  }
  #pragma unroll
  for (int j = 0; j < 64; ++j) {
    float diagv = __shfl(row[j], j);
    float dv = sqrtf(diagv);
    float rinv = 1.0f / dv;
    float myLj = row[j] * rinv;
    row[j] = myLj;
    #pragma unroll
    for (int c = j + 1; c < 64; ++c)
      row[c] = fmaf(-myLj, __shfl(myLj, c), row[c]);
  }
  #pragma unroll
  for (int c = 0; c < 64; ++c)
    Llds[lane * 68 + c] = (c <= lane) ? row[c] : 0.f;
  float w[64];
  #pragma unroll
  for (int r = 0; r < 64; ++r) {
    float s = 0.f;
    #pragma unroll
    for (int kk = 0; kk + 4 <= r; kk += 4) {
      float4 lv = *(const float4*)(Llds + r*68 + kk);
      s += lv.x*w[kk] + lv.y*w[kk+1] + lv.z*w[kk+2] + lv.w*w[kk+3];
    }
    #pragma unroll
    for (int kk = r & ~3; kk < r; ++kk) s += Llds[r*68 + kk] * w[kk];
    float rhs = ((r == lane) ? 1.0f : 0.0f) - s;
    w[r] = rhs / Llds[r*68 + r];   // exact 0 for r < lane
  }
  #pragma unroll
  for (int r = 0; r < 64; ++r) {
    Mk[(size_t)(p0 + r)*DIM + p0 + lane] = w[r];
    Wk[(size_t)(p0 + r)*DIM + p0 + lane] = f2bf(w[r]);
  }
}

// Standalone fdiag for panel 0. One wave per class.
__global__ __launch_bounds__(64) void fdiag_kernel(float* __restrict__ M,
                                                   short* __restrict__ Wb) {
  __shared__ float Llds[64 * 68];
  fdiag_dev(M + (size_t)blockIdx.x * DD, Wb + (size_t)blockIdx.x * DD,
            0, threadIdx.x, Llds);
}

// TRSM for panel p: L_ip = A_ip * inv(p)^T. One WG per (class, i).
// The i==p+1 WG additionally folds the syrk self-update of block (p+1,p+1).
// For the last panel (p==6) the lead WG also chains fdiag(7).
__global__ __launch_bounds__(256) void trsm_kernel(float* __restrict__ M,
                                                   short* __restrict__ Wb, int p) {
  __shared__ float TA[64 * 68];
  __shared__ float TB[64 * 68];
  int n = 7 - p;
  int wg = xcd_swz(blockIdx.x, NCLS * n);
  int cls = wg / n, bi = wg % n;
  int i = p + 1 + bi;
  float* Mk = M + (size_t)cls * DD;
  short* Wk = Wb + (size_t)cls * DD;
  int tid = threadIdx.x;
  int ty = tid >> 4, tx = tid & 15;
  int sr = tid >> 2, sq = (tid & 3) << 4;
  int p0 = p << 6;
  {
    const float* a = Mk + (size_t)((i << 6) + sr)*DIM + p0 + sq;
    const float* b = Mk + (size_t)(p0 + sr)*DIM + p0 + sq;   // inv(p)
    #pragma unroll
    for (int t4 = 0; t4 < 4; ++t4) {
      float4 va = *(const float4*)(a + 4*t4);
      TA[(sq+4*t4+0)*68+sr]=va.x; TA[(sq+4*t4+1)*68+sr]=va.y;
      TA[(sq+4*t4+2)*68+sr]=va.z; TA[(sq+4*t4+3)*68+sr]=va.w;
      float4 vb = *(const float4*)(b + 4*t4);
      TB[(sq+4*t4+0)*68+sr]=vb.x; TB[(sq+4*t4+1)*68+sr]=vb.y;
      TB[(sq+4*t4+2)*68+sr]=vb.z; TB[(sq+4*t4+3)*68+sr]=vb.w;
    }
  }
  __syncthreads();
  float acc[4][4];
  #pragma unroll
  for (int a2 = 0; a2 < 4; ++a2)
    #pragma unroll
    for (int b2 = 0; b2 < 4; ++b2) acc[a2][b2] = 0.f;
  #pragma unroll 16
  for (int m = 0; m < 64; ++m) {
    float4 av = *(const float4*)(TA + m*68 + (ty << 2));
    float4 bv = *(const float4*)(TB + m*68 + (tx << 2));
    float a4[4] = {av.x, av.y, av.z, av.w};
    float b4[4] = {bv.x, bv.y, bv.z, bv.w};
    #pragma unroll
    for (int ir = 0; ir < 4; ++ir)
      #pragma unroll
      for (int ic = 0; ic < 4; ++ic) acc[ir][ic] += a4[ir] * b4[ic];
  }
  #pragma unroll
  for (int q = 0; q < 4; ++q) {
    float4 v; v.x = acc[q][0]; v.y = acc[q][1]; v.z = acc[q][2]; v.w = acc[q][3];
    *(float4*)(Mk + (size_t)((i << 6) + (ty << 2) + q)*DIM + p0 + (tx << 2)) = v;
  }
  if (bi == 0) {   // fold syrk of (p+1,p+1): C -= L*L^T  (L = acc, in-register)
    __syncthreads();   // TA/TB reads done
    #pragma unroll
    for (int q = 0; q < 4; ++q)
      #pragma unroll
      for (int cc = 0; cc < 4; ++cc)
        TA[((tx << 2) + cc)*68 + (ty << 2) + q] = acc[q][cc];   // TA[m][r]=L[r][m]
    __syncthreads();
    float s2[4][4];
    #pragma unroll
    for (int a2 = 0; a2 < 4; ++a2)
      #pragma unroll
      for (int b2 = 0; b2 < 4; ++b2) s2[a2][b2] = 0.f;
    #pragma unroll 16
    for (int m = 0; m < 64; ++m) {
      float4 av = *(const float4*)(TA + m*68 + (ty << 2));
      float4 bv = *(const float4*)(TA + m*68 + (tx << 2));
      float a4[4] = {av.x, av.y, av.z, av.w};
      float b4[4] = {bv.x, bv.y, bv.z, bv.w};
      #pragma unroll
      for (int ir = 0; ir < 4; ++ir)
        #pragma unroll
        for (int ic = 0; ic < 4; ++ic) s2[ir][ic] += a4[ir] * b4[ic];
    }
    int d0 = (p + 1) << 6;
    #pragma unroll
    for (int q = 0; q < 4; ++q) {
      float* dst = Mk + (size_t)(d0 + (ty << 2) + q)*DIM + d0 + (tx << 2);
      float4 v = *(const float4*)dst;
      v.x -= s2[q][0]; v.y -= s2[q][1]; v.z -= s2[q][2]; v.w -= s2[q][3];
      *(float4*)dst = v;
    }
    if (p == 6) {                 // last panel: chain fdiag(7) here
      __syncthreads();            // diag writes drained before wave-0 reads
      if (tid < 64)
        fdiag_dev(Mk, Wk, d0, tid, TB);
    }
  }
}

// Combined launch for panel p: syrkR(p) (all pairs except (p+1,p+1)) in the
// first NCLS*(T-1) WGs, fdiag(p+1) in the last NCLS WGs (hidden under syrk).
__global__ __launch_bounds__(256) void combo_kernel(float* __restrict__ M,
                                                    short* __restrict__ Wb, int p) {
  __shared__ float TA[64 * 68];
  __shared__ float TB[64 * 68];
  int n = 7 - p;
  int T = n * (n + 1) / 2;
  int nsyrk = NCLS * (T - 1);
  int wg = xcd_swz(blockIdx.x, nsyrk + NCLS);
  int tid = threadIdx.x;
  if (wg >= nsyrk) {   // fdiag(p+1)
    int cls = wg - nsyrk;
    if (tid < 64)
      fdiag_dev(M + (size_t)cls * DD, Wb + (size_t)cls * DD,
                (p + 1) << 6, tid, TA);
    return;
  }
  int cls = wg / (T - 1);
  int t = wg % (T - 1) + 1;   // skip t=0 = (p+1,p+1), folded into trsm
  int bi = 0;
  while (t > bi) { t -= bi + 1; ++bi; }
  int i = p + 1 + bi, j = p + 1 + t;
  float* Mk = M + (size_t)cls * DD;
  int ty = tid >> 4, tx = tid & 15;
  int sr = tid >> 2, sq = (tid & 3) << 4;
  {
    const float* a = Mk + (size_t)((i << 6) + sr)*DIM + (p << 6) + sq;
    const float* b = Mk + (size_t)((j << 6) + sr)*DIM + (p << 6) + sq;
    #pragma unroll
    for (int t4 = 0; t4 < 4; ++t4) {
      float4 va = *(const float4*)(a + 4*t4);
      TA[(sq+4*t4+0)*68+sr]=va.x; TA[(sq+4*t4+1)*68+sr]=va.y;
      TA[(sq+4*t4+2)*68+sr]=va.z; TA[(sq+4*t4+3)*68+sr]=va.w;
      float4 vb = *(const float4*)(b + 4*t4);
      TB[(sq+4*t4+0)*68+sr]=vb.x; TB[(sq+4*t4+1)*68+sr]=vb.y;
      TB[(sq+4*t4+2)*68+sr]=vb.z; TB[(sq+4*t4+3)*68+sr]=vb.w;
    }
  }
  __syncthreads();
  float acc[4][4];
  #pragma unroll
  for (int a = 0; a < 4; ++a)
    #pragma unroll
    for (int b = 0; b < 4; ++b) acc[a][b] = 0.f;
  #pragma unroll 16
  for (int m = 0; m < 64; ++m) {
    float4 av = *(const float4*)(TA + m*68 + (ty << 2));
    float4 bv = *(const float4*)(TB + m*68 + (tx << 2));
    float a4[4] = {av.x, av.y, av.z, av.w};
    float b4[4] = {bv.x, bv.y, bv.z, bv.w};
    #pragma unroll
    for (int ir = 0; ir < 4; ++ir)
      #pragma unroll
      for (int ic = 0; ic < 4; ++ic) acc[ir][ic] += a4[ir] * b4[ic];
  }
  #pragma unroll
  for (int q = 0; q < 4; ++q) {
    float* dst = Mk + (size_t)((i << 6) + (ty << 2) + q)*DIM + (j << 6) + (tx << 2);
    float4 v = *(const float4*)dst;
    v.x -= acc[q][0]; v.y -= acc[q][1]; v.z -= acc[q][2]; v.w -= acc[q][3];
    *(float4*)dst = v;
  }
}

// Column sweep: one WG per (class, column j in 0..6). Double-buffered staging.
// j-MAJOR longest-first ordering (j=0 first) so short WGs backfill the tail.
__global__ __launch_bounds__(256) void colsweep_kernel(float* __restrict__ M,
                                                       short* __restrict__ Wb) {
  __shared__ float TL[2][64 * 68];
  __shared__ float TW[2][64 * 68];
  int j = blockIdx.x / NCLS;
  int cls = blockIdx.x % NCLS;
  float* Mk = M + (size_t)cls * DD;
  short* Wk = Wb + (size_t)cls * DD;
  int tid = threadIdx.x;
  int ty = tid >> 4, tx = tid & 15;
  int sr = tid >> 2, sq = (tid & 3) << 4;
  for (int i = j + 1; i < 8; ++i) {
    auto stageLW = [&](int k, int buf) {
      const float* a = Mk + (size_t)((i << 6) + sr)*DIM + (k << 6) + sq;
      const float* b = Mk + (size_t)((j << 6) + sr)*DIM + (k << 6) + sq;
      #pragma unroll
      for (int t4 = 0; t4 < 4; ++t4) {
        float4 va = *(const float4*)(a + 4*t4);
        TL[buf][(sq+4*t4+0)*68+sr]=va.x; TL[buf][(sq+4*t4+1)*68+sr]=va.y;
        TL[buf][(sq+4*t4+2)*68+sr]=va.z; TL[buf][(sq+4*t4+3)*68+sr]=va.w;
        *(float4*)(TW[buf] + sr*68 + sq + 4*t4) = *(const float4*)(b + 4*t4);
      }
    };
    float acc[4][4];
    #pragma unroll
    for (int a = 0; a < 4; ++a)
      #pragma unroll
      for (int b = 0; b < 4; ++b) acc[a][b] = 0.f;
    stageLW(j, 0);
    __syncthreads();
    int cur = 0;
    for (int k = j; k < i; ++k) {
      if (k + 1 < i) stageLW(k + 1, cur ^ 1);   // overlaps GEMM below
      #pragma unroll 16
      for (int m = 0; m < 64; ++m) {
        float4 av = *(const float4*)(TL[cur] + m*68 + (ty << 2));
        float4 bv = *(const float4*)(TW[cur] + m*68 + (tx << 2));
        float a4[4] = {av.x, av.y, av.z, av.w};
        float b4[4] = {bv.x, bv.y, bv.z, bv.w};
        #pragma unroll
        for (int ir = 0; ir < 4; ++ir)
          #pragma unroll
          for (int ic = 0; ic < 4; ++ic) acc[ir][ic] += a4[ir] * b4[ic];
      }
      __syncthreads();
      cur ^= 1;
    }
    #pragma unroll
    for (int q = 0; q < 4; ++q) {
      float4 v; v.x = acc[q][0]; v.y = acc[q][1]; v.z = acc[q][2]; v.w = acc[q][3];
      *(float4*)(TW[0] + ((ty << 2) + q)*68 + (tx << 2)) = v;
    }
    {
      const float* a = Mk + (size_t)((i << 6) + sr)*DIM + (i << 6) + sq;
      #pragma unroll
      for (int t4 = 0; t4 < 4; ++t4) {
        float4 va = *(const float4*)(a + 4*t4);
        TL[0][(sq+4*t4+0)*68+sr]=va.x; TL[0][(sq+4*t4+1)*68+sr]=va.y;
        TL[0][(sq+4*t4+2)*68+sr]=va.z; TL[0][(sq+4*t4+3)*68+sr]=va.w;
      }
    }
    __syncthreads();
    float r2[4][4];
    #pragma unroll
    for (int a = 0; a < 4; ++a)
      #pragma unroll
      for (int b = 0; b < 4; ++b) r2[a][b] = 0.f;
    #pragma unroll 16
    for (int m = 0; m < 64; ++m) {
      float4 av = *(const float4*)(TL[0] + m*68 + (ty << 2));
      float4 bv = *(const float4*)(TW[0] + m*68 + (tx << 2));
      float a4[4] = {av.x, av.y, av.z, av.w};
      float b4[4] = {bv.x, bv.y, bv.z, bv.w};
      #pragma unroll
      for (int ir = 0; ir < 4; ++ir)
        #pragma unroll
        for (int ic = 0; ic < 4; ++ic) r2[ir][ic] += a4[ir] * b4[ic];
    }
    #pragma unroll
    for (int q = 0; q < 4; ++q) {
      int a = (ty << 2) + q;
      float4 v; v.x = -r2[q][0]; v.y = -r2[q][1]; v.z = -r2[q][2]; v.w = -r2[q][3];
      *(float4*)(Mk + (size_t)((j << 6) + a)*DIM + (i << 6) + (tx << 2)) = v;
      s16x4 h;
      h[0] = f2bf(v.x); h[1] = f2bf(v.y); h[2] = f2bf(v.z); h[3] = f2bf(v.w);
      *(s16x4*)(Wk + (size_t)((i << 6) + a)*DIM + (j << 6) + (tx << 2)) = h;
    }
    __syncthreads();   // buffers free for next i
  }
}

// scores via bf16 MFMA. 8-slot ring, TWO tiles per barrier (18 barriers),
// issue -> vmcnt -> barrier ordering (verified round 21): each wave's tiles
// land before the barrier, so the barrier publishes all 4 waves' chunks.
__global__ __launch_bounds__(256) void score_kernel(const float* __restrict__ X,
                                                    const float* __restrict__ muK,
                                                    const float* __restrict__ cK,
                                                    const short* __restrict__ W,
                                                    const float* __restrict__ aux,
                                                    float* __restrict__ out) {
  __shared__ __align__(16) char WB8[8][8192];   // 64 KB ring
  __shared__ float sred[4];
  int bid = blockIdx.x;
  int wg = ((bid & 7) * 400) + (bid >> 3);   // XCD swizzle (3200 = 8*400)
  int kc = wg >> 5;
  int n0 = (wg & 31) << 6;
  int tid = threadIdx.x;
  int lane = tid & 63, wv = tid >> 6;
  const short* Wk = W + (size_t)kc * DD;
  const float* mu = muK + (size_t)kc * DIM;
  int r16 = lane & 15;
  int k8 = (lane >> 4) << 3;
  int arow = (wv << 4) + r16;

  int lrow = lane >> 3;
  int lcolel = ((lane & 7) ^ lrow) << 3;

  constexpr int SJT[36] = {0,1,1, 2,3,2,3,2,3,3, 4,5,4,5,4,5,4,5,4,5,5,
                           6,7,6,7,6,7,6,7,6,7,6,7,6,7,7};
  constexpr int SDC[36] = {0,0,1, 0,0,1,1,2,2,3, 0,0,1,1,2,2,3,3,4,4,5,
                           0,0,1,1,2,2,3,3,4,4,5,5,6,6,7};

  bf16x8 af[8][2];
  #pragma unroll
  for (int dc = 0; dc < 8; ++dc) {
    #pragma unroll
    for (int ks = 0; ks < 2; ++ks) {
      int col = (dc << 6) + (ks << 5) + k8;
      const float* xp = X + (size_t)(n0 + arow)*DIM + col;
      float4 x0 = *(const float4*)xp;
      float4 x1 = *(const float4*)(xp + 4);
      float4 m0 = *(const float4*)(mu + col);
      float4 m1 = *(const float4*)(mu + col + 4);
      bf16x8 h;
      h[0]=f2bf(x0.x-m0.x); h[1]=f2bf(x0.y-m0.y); h[2]=f2bf(x0.z-m0.z); h[3]=f2bf(x0.w-m0.w);
      h[4]=f2bf(x1.x-m1.x); h[5]=f2bf(x1.y-m1.y); h[6]=f2bf(x1.z-m1.z); h[7]=f2bf(x1.w-m1.w);
      af[dc][ks] = h;
    }
  }

  auto issue = [&](int s) {
    const int b = s & 7;
    const int rbase = SJT[s] << 6;
    const int cc = (SDC[s] << 6) + lcolel;
    #pragma unroll
    for (int q = 0; q < 2; ++q) {
      const short* g = Wk + (size_t)(rbase + (q << 5) + (wv << 3) + lrow)*DIM + cc;
      __builtin_amdgcn_global_load_lds(
          (const __attribute__((address_space(1))) void*)g,
          (__attribute__((address_space(3))) void*)(WB8[b] + (q << 12) + (wv << 10)),
          16, 0, 0);
    }
  };

  float qp[4] = {0.f, 0.f, 0.f, 0.f};
  f32x4 acc[2][4];
  #pragma unroll
  for (int a = 0; a < 2; ++a)
    #pragma unroll
    for (int jj = 0; jj < 4; ++jj) { acc[a][jj][0]=0.f; acc[a][jj][1]=0.f; acc[a][jj][2]=0.f; acc[a][jj][3]=0.f; }

  issue(0);
  issue(1);
  issue(2);
  issue(3);
  #pragma unroll
  for (int s = 0; s < 36; ++s) {
    const int jt = SJT[s], dc = SDC[s];
    if ((s & 1) == 0) {                       // one barrier per tile PAIR
      if (s + 4 < 36) issue(s + 4);
      if (s + 5 < 36) issue(s + 5);
      if (s <= 30)      asm volatile("s_waitcnt vmcnt(8)" ::: "memory");
      else if (s == 32) asm volatile("s_waitcnt vmcnt(4)" ::: "memory");
      else              asm volatile("s_waitcnt vmcnt(0)" ::: "memory");
      __builtin_amdgcn_s_barrier();           // tiles s, s+1 visible
      __builtin_amdgcn_sched_barrier(0);      // rule 18
    }
    __builtin_amdgcn_s_setprio(1);
    #pragma unroll
    for (int ks = 0; ks < 2; ++ks) {
      #pragma unroll
      for (int jj = 0; jj < 4; ++jj) {
        int brow = (jj << 4) + r16;
        bf16x8 bfr = *(const bf16x8*)((const char*)WB8[s & 7] +
                     (((brow << 7) + (((ks << 5) + k8) << 1)) ^ ((brow & 7) << 4)));
        acc[jt & 1][jj] = __builtin_amdgcn_mfma_f32_16x16x32_bf16(af[dc][ks], bfr, acc[jt & 1][jj], 0, 0, 0);
      }
    }
    __builtin_amdgcn_s_setprio(0);
    if (s == 2 || s == 9 || s == 20 || s == 35) {   // group end: square & reset
      #pragma unroll
      for (int a = 0; a < 2; ++a)
        #pragma unroll
        for (int jj = 0; jj < 4; ++jj)
          #pragma unroll
          for (int r = 0; r < 4; ++r) {
            float y = acc[a][jj][r]; qp[r] += y * y;
            acc[a][jj][r] = 0.f;
          }
    }
  }
  #pragma unroll
  for (int r = 0; r < 4; ++r) {
    qp[r] += __shfl_xor(qp[r], 1);
    qp[r] += __shfl_xor(qp[r], 2);
    qp[r] += __shfl_xor(qp[r], 4);
    qp[r] += __shfl_xor(qp[r], 8);
  }
  {
    float v = (tid < NCLS) ? cK[tid] : 0.f;
    #pragma unroll
    for (int o = 32; o > 0; o >>= 1) v += __shfl_xor(v, o);
    if (lane == 0) sred[wv] = v;
  }
  __syncthreads();
  float sumck = sred[0] + sred[1] + sred[2] + sred[3];
  float ck = cK[kc];
  float base;
  if (ck == 0.f) base = -INFINITY;
  else base = logf(ck) - logf(sumck) - 0.25f * logf(aux[1 + kc]);
  if ((lane & 15) == 0) {
    int nbase = n0 + (wv << 4) + ((lane >> 4) << 2);
    #pragma unroll
    for (int r = 0; r < 4; ++r)
      out[(size_t)(nbase + r)*NCLS + kc] = base - 0.5f * qp[r];
  }
}

extern "C" void kernel_launch(void* const* d_in, const int* in_sizes, int n_in,
                              void* d_out, int out_size, void* d_ws, size_t ws_size,
                              hipStream_t stream) {
  (void)in_sizes; (void)n_in; (void)out_size; (void)ws_size;
  const float* X      = (const float*)d_in[0];
  const float* muK    = (const float*)d_in[1];
  const float* SigmaK = (const float*)d_in[2];
  const float* Sigma  = (const float*)d_in[3];
  const float* cK     = (const float*)d_in[4];
  float* out = (float*)d_out;
  char* ws = (char*)d_ws;
  float* M   = (float*)ws;                                   // 104857600 B
  short* W   = (short*)(ws + (size_t)NCLS * DD * 4);         //  52428800 B
  float* aux = (float*)(ws + (size_t)NCLS * DD * 6);         //       404 B

  (void)hipMemsetAsync(aux, 0, (1 + NCLS) * sizeof(float), stream);
  prep_kernel<<<400, 256, 0, stream>>>(SigmaK, Sigma, M, aux);
  fdiag_kernel<<<NCLS, 64, 0, stream>>>(M, W);               // inv(0)
  for (int p = 0; p < 7; ++p) {
    int n = 7 - p;
    int T = n * (n + 1) / 2;
    trsm_kernel<<<NCLS * n, 256, 0, stream>>>(M, W, p);      // + fold (+fdiag7 @p=6)
    if (p < 6)
      combo_kernel<<<NCLS * (T - 1) + NCLS, 256, 0, stream>>>(M, W, p);  // syrkR ∥ fdiag(p+1)
  }
  colsweep_kernel<<<NCLS * 7, 256, 0, stream>>>(M, W);
  score_kernel<<<NCLS * 32, 256, 0, stream>>>(X, muK, cK, W, aux, out);
}